// Round 1
// 562.629 us; speedup vs baseline: 1.0170x; 1.0170x over previous
//
#include <hip/hip_runtime.h>
#include <math.h>

// UMGMQuantizer forward = two chained argmax-over-K (logit+gumbel) + codeword gather.
// Round 4: transcendental-tax removal + critical-path shortening.
//  - Screening threshold now fp32 with hardware __logf/__expf. Safe: screening only
//    needs a conservative LOWER bound of gumbel(umax); near u->1 (hot path: max of
//    2048 uniforms) hw log(u) loses absolute accuracy, so -log(u) is computed from
//    an exact e=1-u series, with downward-bias epsilons all << the 0.05 margin.
//  - Survivor gumbels (fp64, exact, unchanged semantics) computed ONE PER LANE in a
//    single parallel pass instead of serially per survivor (~5 serial double-log
//    calls/level -> ~1 parallel pass).
//  - Both u rows (8 KB each) loaded into registers up front: 16 outstanding
//    dwordx4 hide HBM latency under the max-sweep + level-0 compute.
//  - Winning codeword fragment carried in registers (wave-uniform best update), so
//    c0/c1 are never re-gathered on the critical path.
// Exact fp64 survivor scoring (dot butterfly order, c2, gumbel, tie-break) is
// bit-identical to round 3 -> same argmax selection.

namespace {
constexpr int Mm = 8, Kk = 2048, Dd = 128;
constexpr int MK = Mm * Kk;                    // 16384 rows per codebook
constexpr double SQRTK = 45.254833995939045;   // sqrt(2048)

__device__ __forceinline__ double wsum_d(double v) {
#pragma unroll
  for (int o = 32; o > 0; o >>= 1) v += __shfl_xor(v, o);
  return v;
}
__device__ __forceinline__ float wsum_f(float v) {
#pragma unroll
  for (int o = 32; o > 0; o >>= 1) v += __shfl_xor(v, o);
  return v;
}
__device__ __forceinline__ float wmax_f(float v) {
#pragma unroll
  for (int o = 32; o > 0; o >>= 1) v = fmaxf(v, __shfl_xor(v, o));
  return v;
}

// Exact gumbel in fp64 (matches fp64 numpy semantics: clip, log). Survivor scoring.
__device__ __forceinline__ double gumbel_d(float u) {
  double uc = fmin(fmax((double)u, 1e-6), 1.0 - 1e-6);
  return -log(-log(uc));
}

// Conservative (downward-biased) fp32 gumbel lower bound, hw-log based.
// Hazard: for u->1 hw __logf(u) has poor ABSOLUTE accuracy (result ~ -(1-u));
// use the exact-e series there. Bias every step down; total bias ~1e-4 << margin.
__device__ __forceinline__ float gumbel_lb_f(float u) {
  float uc = fminf(fmaxf(u, 1e-6f), 1.0f - 1e-6f);
  float e = 1.0f - uc;                      // exact (Sterbenz) for uc >= 0.5
  float t;                                  // upper bound of -log(uc)
  if (e > 0.04f) {
    t = -__logf(uc);                        // |log| >= 0.04: rel err ~1e-7, fine
  } else {
    // -log(1-e) = e + e^2/2 + e^3/3 + e^4/4 (+ <6e-7 rel trunc at e=0.04)
    t = e * (1.0f + e * (0.5f + e * (0.3333334f + e * 0.25f)));
  }
  t *= 1.000004f;                           // round t up -> gumbel down (safe)
  return -__logf(t) - 2e-5f;                // bias down past hw-log error
}

// prep1: squared row norms of both codebooks (fp64). One wave per row.
__global__ __launch_bounds__(256) void prep1(
    const float* __restrict__ cb0, const float* __restrict__ cb1,
    double* __restrict__ c2d0, double* __restrict__ c2d1) {
  int wid = threadIdx.x >> 6, lane = threadIdx.x & 63;
  int row = blockIdx.x * 4 + wid;              // 0..32767
  int lvl = row >= MK;
  int r = row & (MK - 1);
  const float* cb = lvl ? cb1 : cb0;
  float2 c = ((const float2*)(cb + (size_t)r * Dd))[lane];
  double s = wsum_d((double)c.x * (double)c.x + (double)c.y * (double)c.y);
  if (lane == 0) { if (lvl) c2d1[r] = s; else c2d0[r] = s; }
}

// prep2: per (level,m): Rtab = {w*(c2max-c2min), 4*w*sqrt(c2max)} (conservative).
__global__ __launch_bounds__(256) void prep2(
    const double* __restrict__ c2d0, const double* __restrict__ c2d1,
    const float* __restrict__ t0, const float* __restrict__ t1,
    float2* __restrict__ Rtab) {
  int b = blockIdx.x;                          // 0..15
  int lvl = b >> 3, m = b & 7;
  const double* c2 = (lvl ? c2d1 : c2d0) + m * Kk;
  int tid = threadIdx.x;
  double mx = -1e300, mn = 1e300;
  for (int i = tid; i < Kk; i += 256) { double v = c2[i]; mx = fmax(mx, v); mn = fmin(mn, v); }
#pragma unroll
  for (int o = 32; o > 0; o >>= 1) {
    mx = fmax(mx, __shfl_xor(mx, o));
    mn = fmin(mn, __shfl_xor(mn, o));
  }
  __shared__ double smx[4], smn[4];
  int wid = tid >> 6, lane = tid & 63;
  if (lane == 0) { smx[wid] = mx; smn[wid] = mn; }
  __syncthreads();
  if (tid == 0) {
    mx = fmax(fmax(smx[0], smx[1]), fmax(smx[2], smx[3]));
    mn = fmin(fmin(smn[0], smn[1]), fmin(smn[2], smn[3]));
    double w = (double)fmaxf(lvl ? t1[m] : t0[m], 1e-6f) / SQRTK;
    float2 r;
    r.x = (float)(w * (mx - mn) * 1.0001);
    r.y = (float)(4.0 * w * sqrt(mx) * 1.0001);
    Rtab[b] = r;
  }
}

// One level's exact argmax for one (n,m), executed by a full wave.
// r[8] = this level's u row, preloaded by the caller (latency already paid).
// Returns best k; *bc_out = this lane's float2 fragment of the winning codeword.
__device__ __forceinline__ int do_level(
    float zx, float zy, int lane, float um, const float4* r,
    const float* __restrict__ urow,    // u + (n*M+m)*K
    const float* __restrict__ cbm,     // codebook + m*K*D
    const double* __restrict__ c2m,    // c2d + m*K
    float2 rr, double wd, float2* bc_out) {
  float zn = sqrtf(wsum_f(zx * zx + zy * zy));
  // Wave-uniform conservative threshold, all fp32 hw transcendentals.
  float thr = gumbel_lb_f(um) - (rr.x + rr.y * zn) - 0.05f;
  float uthr = __expf(-__expf(-thr) * 1.000004f) * (1.0f - 4e-6f);  // round down
  // Candidate bitmask straight from registers; bit t=j*4+q <-> k=(j*64+lane)*4+q
  unsigned mask32 = 0;
#pragma unroll
  for (int j = 0; j < 8; ++j) {
    mask32 |= (r[j].x >= uthr ? 1u : 0u) << (j * 4 + 0);
    mask32 |= (r[j].y >= uthr ? 1u : 0u) << (j * 4 + 1);
    mask32 |= (r[j].z >= uthr ? 1u : 0u) << (j * 4 + 2);
    mask32 |= (r[j].w >= uthr ? 1u : 0u) << (j * 4 + 3);
  }
  // Refine survivors exactly in fp64. Outer pass: every survivor-owning lane
  // computes its gumbel SIMULTANEOUSLY (one double-log chain for all of them;
  // second pass only if some lane owns 2+ survivors, ~5% of waves).
  double bestS = -1e300;
  int bestK = 0;
  float2 bc = make_float2(0.f, 0.f);
  for (;;) {
    bool has = (mask32 != 0);
    unsigned long long actv = __ballot(has);
    if (!actv) break;
    int kc = 0;
    double g = 0.0;
    if (has) {
      int t = __builtin_ffs((int)mask32) - 1;
      mask32 &= mask32 - 1;
      kc = ((t >> 2) << 8) + (lane << 2) + (t & 3);
      g = gumbel_d(urow[kc]);            // parallel across survivor lanes
    }
    // Serial exact scoring (short now: no transcendentals inside).
    while (actv) {
      int l = (int)__ffsll(actv) - 1;
      actv &= actv - 1;
      int kcl = __shfl(kc, l);
      double gl = __shfl(g, l);
      float2 c = ((const float2*)(cbm + (size_t)kcl * Dd))[lane];
      double dot = wsum_d((double)zx * (double)c.x + (double)zy * (double)c.y);
      double sc = (2.0 * dot - c2m[kcl]) * wd + gl;  // x2 const dropped
      if (sc > bestS || (sc == bestS && kcl < bestK)) {
        bestS = sc; bestK = kcl; bc = c;  // wave-uniform update; bc = lane's frag
      }
    }
  }
  *bc_out = bc;
  return bestK;
}

__global__ __launch_bounds__(256) void fused_kernel(
    const float* __restrict__ x,
    const float* __restrict__ cb0, const float* __restrict__ cb1,
    const float* __restrict__ t0, const float* __restrict__ t1,
    const float* __restrict__ u0, const float* __restrict__ u1,
    const double* __restrict__ c2d0, const double* __restrict__ c2d1,
    const float2* __restrict__ Rtab,
    float* __restrict__ out) {
  const int wid = threadIdx.x >> 6, lane = threadIdx.x & 63;
  const int p = blockIdx.x * 4 + wid;   // 0..32767, m-major: c2d row stays L2-hot
  const int m = p >> 12;
  const int n = p & 4095;

  const float* u0row = u0 + ((size_t)n * Mm + m) * Kk;
  const float* u1row = u1 + ((size_t)n * Mm + m) * Kk;
  const float4* a4 = (const float4*)u0row;
  const float4* b4 = (const float4*)u1row;

  // Issue BOTH levels' u-row loads up front: 16 outstanding dwordx4 / lane.
  float4 r0[8], r1[8];
#pragma unroll
  for (int j = 0; j < 8; ++j) { r0[j] = a4[j * 64 + lane]; r1[j] = b4[j * 64 + lane]; }

  float2 z = ((const float2*)(x + (size_t)n * 1024 + m * Dd))[lane];
  double wd0 = (double)fmaxf(t0[m], 1e-6f) / SQRTK;
  double wd1 = (double)fmaxf(t1[m], 1e-6f) / SQRTK;

  float um0 = 0.f, um1 = 0.f;
#pragma unroll
  for (int j = 0; j < 8; ++j) {
    um0 = fmaxf(um0, fmaxf(fmaxf(r0[j].x, r0[j].y), fmaxf(r0[j].z, r0[j].w)));
    um1 = fmaxf(um1, fmaxf(fmaxf(r1[j].x, r1[j].y), fmaxf(r1[j].z, r1[j].w)));
  }
  um0 = wmax_f(um0);
  um1 = wmax_f(um1);

  const float* cb0m = cb0 + (size_t)m * Kk * Dd;
  const float* cb1m = cb1 + (size_t)m * Kk * Dd;

  float2 c0, c1;
  (void)do_level(z.x, z.y, lane, um0, r0, u0row, cb0m, c2d0 + m * Kk,
                 Rtab[m], wd0, &c0);
  (void)do_level(z.x - c0.x, z.y - c0.y, lane, um1, r1, u1row, cb1m,
                 c2d1 + m * Kk, Rtab[8 + m], wd1, &c1);

  ((float2*)(out + (size_t)n * 1024 + m * Dd))[lane] =
      make_float2(c0.x + c1.x, c0.y + c1.y);
}
}  // namespace

extern "C" void kernel_launch(void* const* d_in, const int* in_sizes, int n_in,
                              void* d_out, int out_size, void* d_ws, size_t ws_size,
                              hipStream_t stream) {
  const float* x   = (const float*)d_in[0];
  const float* cb0 = (const float*)d_in[1];
  const float* cb1 = (const float*)d_in[2];
  const float* t0  = (const float*)d_in[3];
  const float* t1  = (const float*)d_in[4];
  const float* u0  = (const float*)d_in[5];
  const float* u1  = (const float*)d_in[6];
  float* out = (float*)d_out;

  // ws: c2d0/c2d1 (16384 doubles each) + Rtab (16 float2) = 256 KB + 128 B
  char* ws = (char*)d_ws;
  double* c2d0 = (double*)ws;
  double* c2d1 = c2d0 + MK;
  float2* Rtab = (float2*)(c2d1 + MK);

  prep1<<<8192, 256, 0, stream>>>(cb0, cb1, c2d0, c2d1);
  prep2<<<16, 256, 0, stream>>>(c2d0, c2d1, t0, t1, Rtab);
  fused_kernel<<<8192, 256, 0, stream>>>(x, cb0, cb1, t0, t1, u0, u1,
                                         c2d0, c2d1, Rtab, out);
}